// Round 2
// baseline (1874.102 us; speedup 1.0000x reference)
//
#include <hip/hip_runtime.h>

typedef unsigned short u16;
typedef unsigned int u32;
typedef u16 u16x8 __attribute__((ext_vector_type(8)));
typedef u16 u16x4 __attribute__((ext_vector_type(4)));
typedef __bf16 bf16x8 __attribute__((ext_vector_type(8)));
typedef float f32x4 __attribute__((ext_vector_type(4)));

#define DEV __device__ __forceinline__

DEV u16 f2bf(float f) {
  u32 u = __builtin_bit_cast(u32, f);
  u32 r = u + 0x7fffu + ((u >> 16) & 1u);
  return (u16)(r >> 16);
}

DEV int imin(int a, int b) { return a < b ? a : b; }

DEV void gload_lds16(const void* g, void* l) {
  __builtin_amdgcn_global_load_lds(
      (const __attribute__((address_space(1))) void*)g,
      (__attribute__((address_space(3))) void*)l, 16, 0, 0);
}

// ============ 256x256 8-phase GEMM: C[M,N] = A[M,K] @ Bt[N,K]^T + bias ============
// 512 threads = 8 waves (2 M x 4 N). Per-wave out 128x64. BK=64, dbuf LDS 128 KiB.
// LDS layout XOR-swizzled: byte(row, chunk) = row*128 + ((chunk ^ (row&7))*16),
// realized via pre-swizzled GLOBAL source (global_load_lds dest is linear).
template <int RELU, int OUT_BF16>
__global__ __launch_bounds__(512) void gemm8_kernel(
    const u16* __restrict__ A, const u16* __restrict__ Bt,
    const float* __restrict__ bias, u16* __restrict__ Cb, float* __restrict__ Cf,
    int M, int N, int K) {
  __shared__ __align__(16) u16 As[2][256 * 64];
  __shared__ __align__(16) u16 Bs[2][256 * 64];
  const int t = threadIdx.x, wave = t >> 6, lane = t & 63;
  const int fr = lane & 15, fq = lane >> 4;
  const int wm = wave >> 2, wn = wave & 3;
  const int NT = K >> 6;
  const int nbx = N >> 8;

  int bid = blockIdx.x;
  {  // XCD-aware swizzle (all grids here are %8==0)
    const int cpx = (int)gridDim.x >> 3;
    bid = (bid & 7) * cpx + (bid >> 3);
  }
  const int bx = bid % nbx, by = bid / nbx;
  const int m0 = by << 8, n0 = bx << 8;

  // staging: thread t covers LDS row (t>>3) (+64*j, +128*(h&1)), 16B chunk (t&7);
  // pre-swizzle global chunk index so swizzled data lands under linear LDS writes
  const int srow = t >> 3;
  const int c8 = ((t & 7) ^ (srow & 7)) * 8;
  const u16* aB = A + (size_t)(m0 + srow) * K + c8;
  const u16* bB = Bt + (size_t)(n0 + srow) * K + c8;
  const size_t rK64 = (size_t)64 * K;
  const int ldsW = wave * 1024;  // wave-uniform byte base within an 8 KiB j-slab

  // half h: 0=A rows0-127, 1=A rows128-255, 2=B rows0-127, 3=B rows128-255
  auto STAGE = [&](int buf, int h, int kt) {
    char* lds = (char*)(h < 2 ? As[buf] : Bs[buf]) + (h & 1) * 16384 + ldsW;
    const u16* g = (h < 2 ? aB : bB) + (size_t)(h & 1) * 128 * K + (size_t)kt * 64;
    gload_lds16(g, lds);
    gload_lds16(g + rK64, lds + 8192);
  };

  bf16x8 aF[4][2], bF[4][2];
  f32x4 acc[8][4] = {};

  auto LDA = [&](int buf, int mh) {
    const u16* base = As[buf] + (size_t)(wm * 128 + mh * 64 + fr) * 64;
#pragma unroll
    for (int m = 0; m < 4; ++m)
#pragma unroll
      for (int ks = 0; ks < 2; ++ks)
        aF[m][ks] = *(const bf16x8*)(base + m * 16 * 64 + (((ks * 4 + fq) ^ (fr & 7)) * 8));
  };
  auto LDB2 = [&](int buf, int n00) {
    const u16* base = Bs[buf] + (size_t)(wn * 64 + fr) * 64;
#pragma unroll
    for (int nn = 0; nn < 2; ++nn)
#pragma unroll
      for (int ks = 0; ks < 2; ++ks)
        bF[n00 + nn][ks] =
            *(const bf16x8*)(base + (n00 + nn) * 16 * 64 + (((ks * 4 + fq) ^ (fr & 7)) * 8));
  };
  auto MM16 = [&](int mb, int nb) {
#pragma unroll
    for (int m = 0; m < 4; ++m)
#pragma unroll
      for (int nn = 0; nn < 2; ++nn)
#pragma unroll
        for (int ks = 0; ks < 2; ++ks)
          acc[mb + m][nb + nn] = __builtin_amdgcn_mfma_f32_16x16x32_bf16(
              aF[m][ks], bF[nb + nn][ks], acc[mb + m][nb + nn], 0, 0, 0);
  };

  // prologue: tile0 fully + tile1 h0
  STAGE(0, 0, 0);
  STAGE(0, 1, 0);
  STAGE(0, 2, 0);
  STAGE(0, 3, 0);
  STAGE(1, 0, imin(1, NT - 1));
  asm volatile("s_waitcnt vmcnt(2)" ::: "memory");
  __builtin_amdgcn_s_barrier();

  for (int kt = 0; kt < NT; ++kt) {
    const int cur = kt & 1, nxt = cur ^ 1;
    const int kt1 = imin(kt + 1, NT - 1), kt2 = imin(kt + 2, NT - 1);
    // P0: reads A-mh0(8) + B n0,n1(4); stage h1 of kt+1
    LDA(cur, 0);
    LDB2(cur, 0);
    STAGE(nxt, 1, kt1);
    __builtin_amdgcn_s_barrier();
    asm volatile("s_waitcnt lgkmcnt(0)" ::: "memory");
    __builtin_amdgcn_s_setprio(1);
    MM16(0, 0);
    __builtin_amdgcn_s_setprio(0);
    __builtin_amdgcn_s_barrier();
    // P1: reads B n2,n3(4); stage h2 of kt+1
    LDB2(cur, 2);
    STAGE(nxt, 2, kt1);
    __builtin_amdgcn_s_barrier();
    asm volatile("s_waitcnt lgkmcnt(0)" ::: "memory");
    __builtin_amdgcn_s_setprio(1);
    MM16(0, 2);
    __builtin_amdgcn_s_setprio(0);
    __builtin_amdgcn_s_barrier();
    // P2: reads A-mh1(8); stage h3 of kt+1
    LDA(cur, 1);
    STAGE(nxt, 3, kt1);
    __builtin_amdgcn_s_barrier();
    asm volatile("s_waitcnt lgkmcnt(0)" ::: "memory");
    __builtin_amdgcn_s_setprio(1);
    MM16(4, 2);
    __builtin_amdgcn_s_setprio(0);
    __builtin_amdgcn_s_barrier();
    // P3: no reads; stage h0 of kt+2 into buf[cur]; counted vmcnt gates tile kt+1
    STAGE(cur, 0, kt2);
    asm volatile("s_waitcnt vmcnt(2)" ::: "memory");
    __builtin_amdgcn_s_barrier();
    __builtin_amdgcn_s_setprio(1);
    MM16(4, 0);
    __builtin_amdgcn_s_setprio(0);
    __builtin_amdgcn_s_barrier();
  }
  asm volatile("s_waitcnt vmcnt(0)" ::: "memory");

#pragma unroll
  for (int n = 0; n < 4; ++n) {
    const int col = n0 + wn * 64 + n * 16 + fr;
    const float bvv = bias[col];
#pragma unroll
    for (int mf = 0; mf < 8; ++mf) {
#pragma unroll
      for (int r = 0; r < 4; ++r) {
        const int row = m0 + wm * 128 + mf * 16 + fq * 4 + r;
        float v = acc[mf][n][r] + bvv;
        if (RELU) v = fmaxf(v, 0.f);
        if (OUT_BF16)
          Cb[(size_t)row * N + col] = f2bf(v);
        else
          Cf[(size_t)row * N + col] = v;
      }
    }
  }
}

// ---------------- attention: qkv [B,S,2304] bf16 -> o [B,S,768] f32 ----------------
__global__ __launch_bounds__(256, 2) void attn_kernel(const u16* __restrict__ qkv,
                                                      const int* __restrict__ lens,
                                                      float* __restrict__ o) {
  __shared__ __align__(16) u16 Kl[128 * 64];
  __shared__ __align__(16) u16 Vt[64 * 128];
  __shared__ __align__(16) u16 Pl[4][16 * 128];

  const int bid = blockIdx.x;
  const int qt = bid & 7;
  const int h = (bid >> 3) % 12;
  const int b = bid / 96;
  const int len = lens[b];
  const int t = threadIdx.x, wave = t >> 6, lane = t & 63;
  const int fr = lane & 15, fq = lane >> 4;

  const size_t base = (size_t)b * 512 * 2304;
  const int q0 = qt * 64 + wave * 16;

  bf16x8 qf[2];
#pragma unroll
  for (int ks = 0; ks < 2; ++ks)
    qf[ks] = *(const bf16x8*)(qkv + base + (size_t)(q0 + fr) * 2304 + h * 64 + ks * 32 + fq * 8);

  f32x4 oacc[4] = {};
  float mrow[4], lrow[4];
#pragma unroll
  for (int r = 0; r < 4; ++r) {
    mrow[r] = -1e30f;
    lrow[r] = 0.f;
  }

  for (int kv0 = 0; kv0 < 512; kv0 += 128) {
    if (kv0 >= len) break;
#pragma unroll
    for (int i = 0; i < 4; ++i) {
      const int c = i * 256 + t;
      const int row = c >> 3, ch = c & 7;
      u16x8 kvl = *(const u16x8*)(qkv + base + (size_t)(kv0 + row) * 2304 + 768 + h * 64 + ch * 8);
      *(u16x8*)(Kl + row * 64 + ((ch ^ (row & 7)) * 8)) = kvl;
      u16x8 vvl = *(const u16x8*)(qkv + base + (size_t)(kv0 + row) * 2304 + 1536 + h * 64 + ch * 8);
#pragma unroll
      for (int u = 0; u < 8; ++u) {
        const int d = ch * 8 + u;
        Vt[d * 128 + (((row >> 3) ^ (d & 7)) * 8) + (row & 7)] = vvl[u];
      }
    }
    __syncthreads();

    f32x4 sa[8] = {};
#pragma unroll
    for (int ks = 0; ks < 2; ++ks) {
#pragma unroll
      for (int n = 0; n < 8; ++n) {
        const int colr = n * 16 + fr;
        bf16x8 kf = *(const bf16x8*)(Kl + colr * 64 + (((ks * 4 + fq) ^ (colr & 7)) * 8));
        sa[n] = __builtin_amdgcn_mfma_f32_16x16x32_bf16(qf[ks], kf, sa[n], 0, 0, 0);
      }
    }

    float tm[4] = {-1e30f, -1e30f, -1e30f, -1e30f};
#pragma unroll
    for (int n = 0; n < 8; ++n) {
      const int col = kv0 + n * 16 + fr;
      const bool ok = col < len;
#pragma unroll
      for (int r = 0; r < 4; ++r) {
        const float s = ok ? sa[n][r] * 0.125f : -1e30f;
        sa[n][r] = s;
        tm[r] = fmaxf(tm[r], s);
      }
    }
#pragma unroll
    for (int d = 1; d < 16; d <<= 1)
#pragma unroll
      for (int r = 0; r < 4; ++r) tm[r] = fmaxf(tm[r], __shfl_xor(tm[r], d));

    float al[4], rs[4];
#pragma unroll
    for (int r = 0; r < 4; ++r) {
      const float mn = fmaxf(mrow[r], tm[r]);
      al[r] = __expf(mrow[r] - mn);
      mrow[r] = mn;
      rs[r] = 0.f;
    }
#pragma unroll
    for (int n = 0; n < 8; ++n)
#pragma unroll
      for (int r = 0; r < 4; ++r) {
        const float p = __expf(sa[n][r] - mrow[r]);
        sa[n][r] = p;
        rs[r] += p;
      }
#pragma unroll
    for (int d = 1; d < 16; d <<= 1)
#pragma unroll
      for (int r = 0; r < 4; ++r) rs[r] += __shfl_xor(rs[r], d);
#pragma unroll
    for (int r = 0; r < 4; ++r) lrow[r] = lrow[r] * al[r] + rs[r];
#pragma unroll
    for (int n = 0; n < 4; ++n)
#pragma unroll
      for (int r = 0; r < 4; ++r) oacc[n][r] *= al[r];

    u16* P = &Pl[wave][0];
#pragma unroll
    for (int n = 0; n < 8; ++n) {
      const int col = n * 16 + fr;
#pragma unroll
      for (int r = 0; r < 4; ++r) {
        const int row = fq * 4 + r;
        P[row * 128 + (((col >> 3) ^ (row & 7)) * 8) + (col & 7)] = f2bf(sa[n][r]);
      }
    }
#pragma unroll
    for (int kslot = 0; kslot < 4; ++kslot) {
      const int ch = kslot * 4 + fq;
      bf16x8 pa = *(const bf16x8*)(P + fr * 128 + ((ch ^ (fr & 7)) * 8));
#pragma unroll
      for (int n = 0; n < 4; ++n) {
        const int colv = n * 16 + fr;
        bf16x8 vf = *(const bf16x8*)(Vt + colv * 128 + ((ch ^ (colv & 7)) * 8));
        oacc[n] = __builtin_amdgcn_mfma_f32_16x16x32_bf16(pa, vf, oacc[n], 0, 0, 0);
      }
    }
    __syncthreads();
  }

  const size_t obase = (size_t)b * 512 * 768 + (size_t)q0 * 768 + h * 64;
#pragma unroll
  for (int n = 0; n < 4; ++n)
#pragma unroll
    for (int r = 0; r < 4; ++r)
      o[obase + (size_t)(fq * 4 + r) * 768 + n * 16 + fr] = oacc[n][r] / lrow[r];
}

// ---------------- f32 -> bf16 transpose (out[n][k] = in[k][n]) ----------------
__global__ __launch_bounds__(256) void transpose_one_kernel(const float* __restrict__ in,
                                                            u16* __restrict__ outp, int K,
                                                            int N) {
  __shared__ float tile[64][65];
  const int tx = threadIdx.x & 63, ty = threadIdx.x >> 6;
  const int n0 = blockIdx.x * 64, k0 = blockIdx.y * 64;
#pragma unroll
  for (int i = 0; i < 16; ++i)
    tile[ty + i * 4][tx] = in[(size_t)(k0 + ty + i * 4) * N + n0 + tx];
  __syncthreads();
#pragma unroll
  for (int i = 0; i < 16; ++i)
    outp[(size_t)(n0 + ty + i * 4) * K + k0 + tx] = f2bf(tile[tx][ty + i * 4]);
}

__global__ __launch_bounds__(256) void transpose_qkv_kernel(const float* __restrict__ qw,
                                                            const float* __restrict__ kw,
                                                            const float* __restrict__ vw, int l,
                                                            u16* __restrict__ outp) {
  __shared__ float tile[64][65];
  const int which = blockIdx.z;
  const float* in = (which == 0 ? qw : which == 1 ? kw : vw) + (size_t)l * 768 * 768;
  u16* op = outp + (size_t)which * 768 * 768;
  const int tx = threadIdx.x & 63, ty = threadIdx.x >> 6;
  const int n0 = blockIdx.x * 64, k0 = blockIdx.y * 64;
#pragma unroll
  for (int i = 0; i < 16; ++i)
    tile[ty + i * 4][tx] = in[(size_t)(k0 + ty + i * 4) * 768 + n0 + tx];
  __syncthreads();
#pragma unroll
  for (int i = 0; i < 16; ++i)
    op[(size_t)(n0 + ty + i * 4) * 768 + k0 + tx] = f2bf(tile[tx][ty + i * 4]);
}

// ---------------- input projection ----------------
__global__ __launch_bounds__(256) void inproj_kernel(const float* __restrict__ x,
                                                     const float* __restrict__ in_w,
                                                     const float* __restrict__ in_b,
                                                     const float* __restrict__ pos,
                                                     float* __restrict__ h,
                                                     u16* __restrict__ hbf) {
  __shared__ float xs[8][32];
  const int t = threadIdx.x;
  const int row0 = blockIdx.x * 8;
  xs[t >> 5][t & 31] = x[(size_t)row0 * 32 + t];
  __syncthreads();
#pragma unroll
  for (int j = 0; j < 3; ++j) {
    const int d = t + j * 256;
    float acc[8] = {};
#pragma unroll
    for (int i = 0; i < 32; ++i) {
      const float wv = in_w[i * 768 + d];
#pragma unroll
      for (int r = 0; r < 8; ++r) acc[r] += xs[r][i] * wv;
    }
    const float bb = in_b[d];
#pragma unroll
    for (int r = 0; r < 8; ++r) {
      const int row = row0 + r;
      const int s = row & 511;
      const float v = acc[r] + bb + pos[(size_t)s * 768 + d];
      h[(size_t)row * 768 + d] = v;
      hbf[(size_t)row * 768 + d] = f2bf(v);
    }
  }
}

// ---------------- LayerNorm(hin + delta): wave-per-row, f32x4 ----------------
__global__ __launch_bounds__(256) void ln_kernel(const float* __restrict__ hin,
                                                 const float* __restrict__ delta,
                                                 const float* __restrict__ g,
                                                 const float* __restrict__ bb,
                                                 float* __restrict__ hout,
                                                 u16* __restrict__ hbf) {
  const int row = blockIdx.x * 4 + (threadIdx.x >> 6);
  const int lane = threadIdx.x & 63;
  const size_t rb = (size_t)row * 768 + lane * 4;
  f32x4 xv[3];
  float s = 0.f, s2 = 0.f;
#pragma unroll
  for (int j = 0; j < 3; ++j) {
    f32x4 a = *(const f32x4*)(hin + rb + j * 256);
    f32x4 d = *(const f32x4*)(delta + rb + j * 256);
    f32x4 v = a + d;
    xv[j] = v;
    s += v[0] + v[1] + v[2] + v[3];
    s2 += v[0] * v[0] + v[1] * v[1] + v[2] * v[2] + v[3] * v[3];
  }
#pragma unroll
  for (int d = 1; d < 64; d <<= 1) {
    s += __shfl_xor(s, d);
    s2 += __shfl_xor(s2, d);
  }
  const float mean = s * (1.f / 768.f);
  const float var = fmaxf(s2 * (1.f / 768.f) - mean * mean, 0.f);
  const float rstd = rsqrtf(var + 1e-5f);
#pragma unroll
  for (int j = 0; j < 3; ++j) {
    f32x4 gv = *(const f32x4*)(g + lane * 4 + j * 256);
    f32x4 bv = *(const f32x4*)(bb + lane * 4 + j * 256);
    f32x4 y;
    u16x4 yb;
#pragma unroll
    for (int c = 0; c < 4; ++c) {
      y[c] = (xv[j][c] - mean) * rstd * gv[c] + bv[c];
      yb[c] = f2bf(y[c]);
    }
    *(f32x4*)(hout + rb + j * 256) = y;
    *(u16x4*)(hbf + rb + j * 256) = yb;
  }
}

// ---------------- masked mean pool + out projection (2-stage) ----------------
__global__ __launch_bounds__(256) void pool1_kernel(const float* __restrict__ h,
                                                    const int* __restrict__ lens,
                                                    const float* __restrict__ ow,
                                                    float* __restrict__ wsp) {
  const int b = blockIdx.x >> 3, chunk = blockIdx.x & 7;
  const int len = lens[b];
  const int t = threadIdx.x;
  const int s0 = chunk * 64;
  const int s1 = imin(s0 + 64, len);
  float acc0 = 0.f, acc1 = 0.f, acc2 = 0.f;
  const float* hp = h + (size_t)b * 512 * 768;
  for (int s = s0; s < s1; ++s) {
    const size_t rb = (size_t)s * 768;
    acc0 += hp[rb + t];
    acc1 += hp[rb + t + 256];
    acc2 += hp[rb + t + 512];
  }
  float part = acc0 * ow[t] + acc1 * ow[t + 256] + acc2 * ow[t + 512];
#pragma unroll
  for (int d = 1; d < 64; d <<= 1) part += __shfl_xor(part, d);
  __shared__ float ps[4];
  if ((t & 63) == 0) ps[t >> 6] = part;
  __syncthreads();
  if (t == 0) wsp[blockIdx.x] = ps[0] + ps[1] + ps[2] + ps[3];
}

__global__ void pool2_kernel(const float* __restrict__ wsp, const int* __restrict__ lens,
                             const float* __restrict__ ob, float* __restrict__ out) {
  const int b = threadIdx.x;
  if (b < 16) {
    float s = 0.f;
#pragma unroll
    for (int c = 0; c < 8; ++c) s += wsp[b * 8 + c];
    out[b] = s / (float)lens[b] + ob[0];
  }
}

__global__ void biaspack_kernel(const float* __restrict__ qb, const float* __restrict__ kb,
                                const float* __restrict__ vb, float* __restrict__ qkvb) {
  const int i = blockIdx.x * 256 + threadIdx.x;
  if (i >= 6 * 2304) return;
  const int l = i / 2304, j = i % 2304;
  float v;
  if (j < 768)
    v = qb[l * 768 + j];
  else if (j < 1536)
    v = kb[l * 768 + j - 768];
  else
    v = vb[l * 768 + j - 1536];
  qkvb[i] = v;
}

extern "C" void kernel_launch(void* const* d_in, const int* in_sizes, int n_in, void* d_out,
                              int out_size, void* d_ws, size_t ws_size, hipStream_t stream) {
  const float* x = (const float*)d_in[0];
  const int* lens = (const int*)d_in[1];
  const float* in_w = (const float*)d_in[2];
  const float* in_b = (const float*)d_in[3];
  const float* pos = (const float*)d_in[4];
  const float* qw = (const float*)d_in[5];
  const float* qb = (const float*)d_in[6];
  const float* kw = (const float*)d_in[7];
  const float* kb = (const float*)d_in[8];
  const float* vw = (const float*)d_in[9];
  const float* vb = (const float*)d_in[10];
  const float* w1 = (const float*)d_in[11];
  const float* b1 = (const float*)d_in[12];
  const float* w2 = (const float*)d_in[13];
  const float* b2 = (const float*)d_in[14];
  const float* ln1g = (const float*)d_in[15];
  const float* ln1b = (const float*)d_in[16];
  const float* ln2g = (const float*)d_in[17];
  const float* ln2b = (const float*)d_in[18];
  const float* ow = (const float*)d_in[19];
  const float* ob = (const float*)d_in[20];
  float* out = (float*)d_out;

  char* w = (char*)d_ws;
  size_t off = 0;
  auto alloc = [&](size_t bytes) -> void* {
    void* p = w + off;
    off += (bytes + 255) & ~(size_t)255;
    return p;
  };
  u16* qkvt = (u16*)alloc((size_t)2304 * 768 * 2);
  u16* w1t = (u16*)alloc((size_t)3072 * 768 * 2);
  u16* w2t = (u16*)alloc((size_t)768 * 3072 * 2);
  float* qkvb = (float*)alloc((size_t)6 * 2304 * 4);
  float* h = (float*)alloc((size_t)8192 * 768 * 4);
  u16* hbf = (u16*)alloc((size_t)8192 * 768 * 2);
  float* obuf = (float*)alloc((size_t)8192 * 768 * 4);
  u16* ubuf = (u16*)alloc((size_t)8192 * 3072 * 2);  // union: qkv / ff
  float* wsp = (float*)alloc((size_t)128 * 4);
  u16* qkvbuf = ubuf;
  u16* ffbuf = ubuf;

  biaspack_kernel<<<(6 * 2304 + 255) / 256, 256, 0, stream>>>(qb, kb, vb, qkvb);
  inproj_kernel<<<1024, 256, 0, stream>>>(x, in_w, in_b, pos, h, hbf);

  for (int l = 0; l < 6; ++l) {
    transpose_qkv_kernel<<<dim3(12, 12, 3), 256, 0, stream>>>(qw, kw, vw, l, qkvt);
    gemm8_kernel<0, 1><<<32 * 9, 512, 0, stream>>>(hbf, qkvt, qkvb + l * 2304, qkvbuf, nullptr,
                                                   8192, 2304, 768);
    attn_kernel<<<1536, 256, 0, stream>>>(qkvbuf, lens, obuf);
    ln_kernel<<<2048, 256, 0, stream>>>(h, obuf, ln1g + l * 768, ln1b + l * 768, h, hbf);
    transpose_one_kernel<<<dim3(48, 12), 256, 0, stream>>>(w1 + (size_t)l * 768 * 3072, w1t, 768,
                                                           3072);
    gemm8_kernel<1, 1><<<32 * 12, 512, 0, stream>>>(hbf, w1t, b1 + l * 3072, ffbuf, nullptr, 8192,
                                                    3072, 768);
    transpose_one_kernel<<<dim3(12, 48), 256, 0, stream>>>(w2 + (size_t)l * 3072 * 768, w2t, 3072,
                                                           768);
    gemm8_kernel<0, 0><<<32 * 3, 512, 0, stream>>>(ffbuf, w2t, b2 + l * 768, nullptr, obuf, 8192,
                                                   768, 3072);
    ln_kernel<<<2048, 256, 0, stream>>>(h, obuf, ln2g + l * 768, ln2b + l * 768, h, hbf);
  }
  pool1_kernel<<<128, 256, 0, stream>>>(h, lens, ow, wsp);
  pool2_kernel<<<1, 64, 0, stream>>>(wsp, lens, ob, out);
  (void)in_sizes;
  (void)n_in;
  (void)out_size;
  (void)ws_size;
}

// Round 3
// 1739.573 us; speedup vs baseline: 1.0773x; 1.0773x over previous
//
#include <hip/hip_runtime.h>

typedef unsigned short u16;
typedef unsigned int u32;
typedef u16 u16x8 __attribute__((ext_vector_type(8)));
typedef u16 u16x4 __attribute__((ext_vector_type(4)));
typedef __bf16 bf16x8 __attribute__((ext_vector_type(8)));
typedef float f32x4 __attribute__((ext_vector_type(4)));

#define DEV __device__ __forceinline__

DEV u16 f2bf(float f) {
  u32 u = __builtin_bit_cast(u32, f);
  u32 r = u + 0x7fffu + ((u >> 16) & 1u);
  return (u16)(r >> 16);
}

DEV int imin(int a, int b) { return a < b ? a : b; }

DEV void gload_lds16(const void* g, void* l) {
  __builtin_amdgcn_global_load_lds(
      (const __attribute__((address_space(1))) void*)g,
      (__attribute__((address_space(3))) void*)l, 16, 0, 0);
}

// ============ 256x256 8-phase GEMM: C[M,N] = A[M,K] @ Bt[N,K]^T + bias ============
// 512 threads = 8 waves (2 M x 4 N). Per-wave out 128x64. BK=64, dbuf LDS 128 KiB.
// ksub = K-extent this block iterates; ld = row stride of A and Bt (full K).
// nsplit: split-K partials; sp-th part offsets A/Bt cols by sp*ksub, writes Cf+sp*M*N.
// Staging: ALL 4 half-tiles of kt+2 batched in P3 (buf[cur] free after P2),
// gated by counted vmcnt(8) -> each batch has 4 phases (~1 K-tile) of flight.
template <int RELU, int OUT_BF16>
__global__ __launch_bounds__(512) void gemm8_kernel(
    const u16* __restrict__ A, const u16* __restrict__ Bt,
    const float* __restrict__ bias, u16* __restrict__ Cb, float* __restrict__ Cf,
    int M, int N, int ksub, int ld, int nsplit) {
  __shared__ __align__(16) u16 As[2][256 * 64];
  __shared__ __align__(16) u16 Bs[2][256 * 64];
  const int t = threadIdx.x, wave = t >> 6, lane = t & 63;
  const int fr = lane & 15, fq = lane >> 4;
  const int wm = wave >> 2, wn = wave & 3;
  const int NT = ksub >> 6;
  const int nbx = N >> 8;
  const int tiles = nbx * (M >> 8);

  int bid = blockIdx.x;
  {  // XCD-aware swizzle (all grids here are %8==0)
    const int cpx = (int)gridDim.x >> 3;
    bid = (bid & 7) * cpx + (bid >> 3);
  }
  const int sp = bid / tiles;
  bid -= sp * tiles;
  const int bx = bid % nbx, by = bid / nbx;
  const int m0 = by << 8, n0 = bx << 8;
  const u16* Ap = A + (size_t)sp * ksub;
  const u16* Bp = Bt + (size_t)sp * ksub;

  // staging: thread t covers LDS row (t>>3) (+64*j, +128*(h&1)), 16B chunk (t&7);
  // pre-swizzle global chunk index so swizzled data lands under linear LDS writes
  const int srow = t >> 3;
  const int c8 = ((t & 7) ^ (srow & 7)) * 8;
  const u16* aB = Ap + (size_t)(m0 + srow) * ld + c8;
  const u16* bB = Bp + (size_t)(n0 + srow) * ld + c8;
  const size_t rK64 = (size_t)64 * ld;
  const int ldsW = wave * 1024;  // wave-uniform byte base within an 8 KiB j-slab

  // half h: 0=A rows0-127, 1=A rows128-255, 2=B rows0-127, 3=B rows128-255
  auto STAGE = [&](int buf, int h, int kt) {
    char* lds = (char*)(h < 2 ? As[buf] : Bs[buf]) + (h & 1) * 16384 + ldsW;
    const u16* g = (h < 2 ? aB : bB) + (size_t)(h & 1) * 128 * ld + (size_t)kt * 64;
    gload_lds16(g, lds);
    gload_lds16(g + rK64, lds + 8192);
  };
  auto STAGE4 = [&](int buf, int kt) {
    STAGE(buf, 0, kt);
    STAGE(buf, 1, kt);
    STAGE(buf, 2, kt);
    STAGE(buf, 3, kt);
  };

  bf16x8 aF[4][2], bF[4][2];
  f32x4 acc[8][4] = {};

  auto LDA = [&](int buf, int mh) {
    const u16* base = As[buf] + (size_t)(wm * 128 + mh * 64 + fr) * 64;
#pragma unroll
    for (int m = 0; m < 4; ++m)
#pragma unroll
      for (int ks = 0; ks < 2; ++ks)
        aF[m][ks] = *(const bf16x8*)(base + m * 16 * 64 + (((ks * 4 + fq) ^ (fr & 7)) * 8));
  };
  auto LDB2 = [&](int buf, int n00) {
    const u16* base = Bs[buf] + (size_t)(wn * 64 + fr) * 64;
#pragma unroll
    for (int nn = 0; nn < 2; ++nn)
#pragma unroll
      for (int ks = 0; ks < 2; ++ks)
        bF[n00 + nn][ks] =
            *(const bf16x8*)(base + (n00 + nn) * 16 * 64 + (((ks * 4 + fq) ^ (fr & 7)) * 8));
  };
  auto MM16 = [&](int mb, int nb) {
#pragma unroll
    for (int m = 0; m < 4; ++m)
#pragma unroll
      for (int nn = 0; nn < 2; ++nn)
#pragma unroll
        for (int ks = 0; ks < 2; ++ks)
          acc[mb + m][nb + nn] = __builtin_amdgcn_mfma_f32_16x16x32_bf16(
              aF[m][ks], bF[nb + nn][ks], acc[mb + m][nb + nn], 0, 0, 0);
  };

  // prologue: tile0 -> buf0, tile1 -> buf1; gate tile0 (tile1's 8 stay in flight)
  STAGE4(0, 0);
  STAGE4(1, imin(1, NT - 1));
  asm volatile("s_waitcnt vmcnt(8)" ::: "memory");
  __builtin_amdgcn_s_barrier();

  for (int kt = 0; kt < NT; ++kt) {
    const int cur = kt & 1;
    const int kt2 = imin(kt + 2, NT - 1);
    // P0: read A-mh0 (8) + B n0,n1 (4)
    LDA(cur, 0);
    LDB2(cur, 0);
    __builtin_amdgcn_s_barrier();
    asm volatile("s_waitcnt lgkmcnt(0)" ::: "memory");
    __builtin_amdgcn_s_setprio(1);
    MM16(0, 0);
    __builtin_amdgcn_s_setprio(0);
    __builtin_amdgcn_s_barrier();
    // P1: read B n2,n3 (4)
    LDB2(cur, 2);
    __builtin_amdgcn_s_barrier();
    asm volatile("s_waitcnt lgkmcnt(0)" ::: "memory");
    __builtin_amdgcn_s_setprio(1);
    MM16(0, 2);
    __builtin_amdgcn_s_setprio(0);
    __builtin_amdgcn_s_barrier();
    // P2: read A-mh1 (8) — last reads of buf[cur]
    LDA(cur, 1);
    __builtin_amdgcn_s_barrier();
    asm volatile("s_waitcnt lgkmcnt(0)" ::: "memory");
    __builtin_amdgcn_s_setprio(1);
    MM16(4, 2);
    __builtin_amdgcn_s_setprio(0);
    __builtin_amdgcn_s_barrier();
    // P3: buf[cur] now free -> batch-stage tile kt+2 into it; counted gate for kt+1
    STAGE4(cur, kt2);
    asm volatile("s_waitcnt vmcnt(8)" ::: "memory");
    __builtin_amdgcn_s_barrier();
    __builtin_amdgcn_s_setprio(1);
    MM16(4, 0);
    __builtin_amdgcn_s_setprio(0);
    __builtin_amdgcn_s_barrier();
  }
  asm volatile("s_waitcnt vmcnt(0)" ::: "memory");

#pragma unroll
  for (int n = 0; n < 4; ++n) {
    const int col = n0 + wn * 64 + n * 16 + fr;
    const float bvv = (nsplit == 1 || sp == 0) ? bias[col] : 0.f;
#pragma unroll
    for (int mf = 0; mf < 8; ++mf) {
#pragma unroll
      for (int r = 0; r < 4; ++r) {
        const int row = m0 + wm * 128 + mf * 16 + fq * 4 + r;
        float v = acc[mf][n][r] + bvv;
        if (RELU) v = fmaxf(v, 0.f);
        if (OUT_BF16)
          Cb[(size_t)row * N + col] = f2bf(v);
        else
          Cf[(size_t)sp * M * N + (size_t)row * N + col] = v;
      }
    }
  }
}

// ---------------- attention: qkv [B,S,2304] bf16 -> o [B,S,768] f32 ----------------
__global__ __launch_bounds__(256, 2) void attn_kernel(const u16* __restrict__ qkv,
                                                      const int* __restrict__ lens,
                                                      float* __restrict__ o) {
  __shared__ __align__(16) u16 Kl[128 * 64];
  __shared__ __align__(16) u16 Vt[64 * 128];
  __shared__ __align__(16) u16 Pl[4][16 * 128];

  const int bid = blockIdx.x;
  const int qt = bid & 7;
  const int h = (bid >> 3) % 12;
  const int b = bid / 96;
  const int len = lens[b];
  const int t = threadIdx.x, wave = t >> 6, lane = t & 63;
  const int fr = lane & 15, fq = lane >> 4;

  const size_t base = (size_t)b * 512 * 2304;
  const int q0 = qt * 64 + wave * 16;

  bf16x8 qf[2];
#pragma unroll
  for (int ks = 0; ks < 2; ++ks)
    qf[ks] = *(const bf16x8*)(qkv + base + (size_t)(q0 + fr) * 2304 + h * 64 + ks * 32 + fq * 8);

  f32x4 oacc[4] = {};
  float mrow[4], lrow[4];
#pragma unroll
  for (int r = 0; r < 4; ++r) {
    mrow[r] = -1e30f;
    lrow[r] = 0.f;
  }

  for (int kv0 = 0; kv0 < 512; kv0 += 128) {
    if (kv0 >= len) break;
#pragma unroll
    for (int i = 0; i < 4; ++i) {
      const int c = i * 256 + t;
      const int row = c >> 3, ch = c & 7;
      u16x8 kvl = *(const u16x8*)(qkv + base + (size_t)(kv0 + row) * 2304 + 768 + h * 64 + ch * 8);
      *(u16x8*)(Kl + row * 64 + ((ch ^ (row & 7)) * 8)) = kvl;
      u16x8 vvl = *(const u16x8*)(qkv + base + (size_t)(kv0 + row) * 2304 + 1536 + h * 64 + ch * 8);
#pragma unroll
      for (int u = 0; u < 8; ++u) {
        const int d = ch * 8 + u;
        Vt[d * 128 + (((row >> 3) ^ (d & 7)) * 8) + (row & 7)] = vvl[u];
      }
    }
    __syncthreads();

    f32x4 sa[8] = {};
#pragma unroll
    for (int ks = 0; ks < 2; ++ks) {
#pragma unroll
      for (int n = 0; n < 8; ++n) {
        const int colr = n * 16 + fr;
        bf16x8 kf = *(const bf16x8*)(Kl + colr * 64 + (((ks * 4 + fq) ^ (colr & 7)) * 8));
        sa[n] = __builtin_amdgcn_mfma_f32_16x16x32_bf16(qf[ks], kf, sa[n], 0, 0, 0);
      }
    }

    float tm[4] = {-1e30f, -1e30f, -1e30f, -1e30f};
#pragma unroll
    for (int n = 0; n < 8; ++n) {
      const int col = kv0 + n * 16 + fr;
      const bool ok = col < len;
#pragma unroll
      for (int r = 0; r < 4; ++r) {
        const float s = ok ? sa[n][r] * 0.125f : -1e30f;
        sa[n][r] = s;
        tm[r] = fmaxf(tm[r], s);
      }
    }
#pragma unroll
    for (int d = 1; d < 16; d <<= 1)
#pragma unroll
      for (int r = 0; r < 4; ++r) tm[r] = fmaxf(tm[r], __shfl_xor(tm[r], d));

    float al[4], rs[4];
#pragma unroll
    for (int r = 0; r < 4; ++r) {
      const float mn = fmaxf(mrow[r], tm[r]);
      al[r] = __expf(mrow[r] - mn);
      mrow[r] = mn;
      rs[r] = 0.f;
    }
#pragma unroll
    for (int n = 0; n < 8; ++n)
#pragma unroll
      for (int r = 0; r < 4; ++r) {
        const float p = __expf(sa[n][r] - mrow[r]);
        sa[n][r] = p;
        rs[r] += p;
      }
#pragma unroll
    for (int d = 1; d < 16; d <<= 1)
#pragma unroll
      for (int r = 0; r < 4; ++r) rs[r] += __shfl_xor(rs[r], d);
#pragma unroll
    for (int r = 0; r < 4; ++r) lrow[r] = lrow[r] * al[r] + rs[r];
#pragma unroll
    for (int n = 0; n < 4; ++n)
#pragma unroll
      for (int r = 0; r < 4; ++r) oacc[n][r] *= al[r];

    u16* P = &Pl[wave][0];
#pragma unroll
    for (int n = 0; n < 8; ++n) {
      const int col = n * 16 + fr;
#pragma unroll
      for (int r = 0; r < 4; ++r) {
        const int row = fq * 4 + r;
        P[row * 128 + (((col >> 3) ^ (row & 7)) * 8) + (col & 7)] = f2bf(sa[n][r]);
      }
    }
#pragma unroll
    for (int kslot = 0; kslot < 4; ++kslot) {
      const int ch = kslot * 4 + fq;
      bf16x8 pa = *(const bf16x8*)(P + fr * 128 + ((ch ^ (fr & 7)) * 8));
#pragma unroll
      for (int n = 0; n < 4; ++n) {
        const int colv = n * 16 + fr;
        bf16x8 vf = *(const bf16x8*)(Vt + colv * 128 + ((ch ^ (colv & 7)) * 8));
        oacc[n] = __builtin_amdgcn_mfma_f32_16x16x32_bf16(pa, vf, oacc[n], 0, 0, 0);
      }
    }
    __syncthreads();
  }

  const size_t obase = (size_t)b * 512 * 768 + (size_t)q0 * 768 + h * 64;
#pragma unroll
  for (int n = 0; n < 4; ++n)
#pragma unroll
    for (int r = 0; r < 4; ++r)
      o[obase + (size_t)(fq * 4 + r) * 768 + n * 16 + fr] = oacc[n][r] / lrow[r];
}

// ---------------- f32 -> bf16 transpose (out[n][k] = in[k][n]) ----------------
__global__ __launch_bounds__(256) void transpose_one_kernel(const float* __restrict__ in,
                                                            u16* __restrict__ outp, int K,
                                                            int N) {
  __shared__ float tile[64][65];
  const int tx = threadIdx.x & 63, ty = threadIdx.x >> 6;
  const int n0 = blockIdx.x * 64, k0 = blockIdx.y * 64;
#pragma unroll
  for (int i = 0; i < 16; ++i)
    tile[ty + i * 4][tx] = in[(size_t)(k0 + ty + i * 4) * N + n0 + tx];
  __syncthreads();
#pragma unroll
  for (int i = 0; i < 16; ++i)
    outp[(size_t)(n0 + ty + i * 4) * K + k0 + tx] = f2bf(tile[tx][ty + i * 4]);
}

__global__ __launch_bounds__(256) void transpose_qkv_kernel(const float* __restrict__ qw,
                                                            const float* __restrict__ kw,
                                                            const float* __restrict__ vw, int l,
                                                            u16* __restrict__ outp) {
  __shared__ float tile[64][65];
  const int which = blockIdx.z;
  const float* in = (which == 0 ? qw : which == 1 ? kw : vw) + (size_t)l * 768 * 768;
  u16* op = outp + (size_t)which * 768 * 768;
  const int tx = threadIdx.x & 63, ty = threadIdx.x >> 6;
  const int n0 = blockIdx.x * 64, k0 = blockIdx.y * 64;
#pragma unroll
  for (int i = 0; i < 16; ++i)
    tile[ty + i * 4][tx] = in[(size_t)(k0 + ty + i * 4) * 768 + n0 + tx];
  __syncthreads();
#pragma unroll
  for (int i = 0; i < 16; ++i)
    op[(size_t)(n0 + ty + i * 4) * 768 + k0 + tx] = f2bf(tile[tx][ty + i * 4]);
}

// ---------------- input projection ----------------
__global__ __launch_bounds__(256) void inproj_kernel(const float* __restrict__ x,
                                                     const float* __restrict__ in_w,
                                                     const float* __restrict__ in_b,
                                                     const float* __restrict__ pos,
                                                     float* __restrict__ h,
                                                     u16* __restrict__ hbf) {
  __shared__ float xs[8][32];
  const int t = threadIdx.x;
  const int row0 = blockIdx.x * 8;
  xs[t >> 5][t & 31] = x[(size_t)row0 * 32 + t];
  __syncthreads();
#pragma unroll
  for (int j = 0; j < 3; ++j) {
    const int d = t + j * 256;
    float acc[8] = {};
#pragma unroll
    for (int i = 0; i < 32; ++i) {
      const float wv = in_w[i * 768 + d];
#pragma unroll
      for (int r = 0; r < 8; ++r) acc[r] += xs[r][i] * wv;
    }
    const float bb = in_b[d];
#pragma unroll
    for (int r = 0; r < 8; ++r) {
      const int row = row0 + r;
      const int s = row & 511;
      const float v = acc[r] + bb + pos[(size_t)s * 768 + d];
      h[(size_t)row * 768 + d] = v;
      hbf[(size_t)row * 768 + d] = f2bf(v);
    }
  }
}

// ---------------- LayerNorm(hin + d0 [+ d1]): wave-per-row, f32x4 ----------------
template <int ND>
__global__ __launch_bounds__(256) void ln_kernel(const float* __restrict__ hin,
                                                 const float* __restrict__ d0,
                                                 const float* __restrict__ d1,
                                                 const float* __restrict__ g,
                                                 const float* __restrict__ bb,
                                                 float* __restrict__ hout,
                                                 u16* __restrict__ hbf) {
  const int row = blockIdx.x * 4 + (threadIdx.x >> 6);
  const int lane = threadIdx.x & 63;
  const size_t rb = (size_t)row * 768 + lane * 4;
  f32x4 xv[3];
  float s = 0.f, s2 = 0.f;
#pragma unroll
  for (int j = 0; j < 3; ++j) {
    f32x4 a = *(const f32x4*)(hin + rb + j * 256);
    f32x4 d = *(const f32x4*)(d0 + rb + j * 256);
    f32x4 v = a + d;
    if (ND == 2) {
      f32x4 e = *(const f32x4*)(d1 + rb + j * 256);
      v = v + e;
    }
    xv[j] = v;
    s += v[0] + v[1] + v[2] + v[3];
    s2 += v[0] * v[0] + v[1] * v[1] + v[2] * v[2] + v[3] * v[3];
  }
#pragma unroll
  for (int d = 1; d < 64; d <<= 1) {
    s += __shfl_xor(s, d);
    s2 += __shfl_xor(s2, d);
  }
  const float mean = s * (1.f / 768.f);
  const float var = fmaxf(s2 * (1.f / 768.f) - mean * mean, 0.f);
  const float rstd = rsqrtf(var + 1e-5f);
#pragma unroll
  for (int j = 0; j < 3; ++j) {
    f32x4 gv = *(const f32x4*)(g + lane * 4 + j * 256);
    f32x4 bv = *(const f32x4*)(bb + lane * 4 + j * 256);
    f32x4 y;
    u16x4 yb;
#pragma unroll
    for (int c = 0; c < 4; ++c) {
      y[c] = (xv[j][c] - mean) * rstd * gv[c] + bv[c];
      yb[c] = f2bf(y[c]);
    }
    *(f32x4*)(hout + rb + j * 256) = y;
    *(u16x4*)(hbf + rb + j * 256) = yb;
  }
}

// ---------------- masked mean pool + out projection (2-stage) ----------------
__global__ __launch_bounds__(256) void pool1_kernel(const float* __restrict__ h,
                                                    const int* __restrict__ lens,
                                                    const float* __restrict__ ow,
                                                    float* __restrict__ wsp) {
  const int b = blockIdx.x >> 3, chunk = blockIdx.x & 7;
  const int len = lens[b];
  const int t = threadIdx.x;
  const int s0 = chunk * 64;
  const int s1 = imin(s0 + 64, len);
  float acc0 = 0.f, acc1 = 0.f, acc2 = 0.f;
  const float* hp = h + (size_t)b * 512 * 768;
  for (int s = s0; s < s1; ++s) {
    const size_t rb = (size_t)s * 768;
    acc0 += hp[rb + t];
    acc1 += hp[rb + t + 256];
    acc2 += hp[rb + t + 512];
  }
  float part = acc0 * ow[t] + acc1 * ow[t + 256] + acc2 * ow[t + 512];
#pragma unroll
  for (int d = 1; d < 64; d <<= 1) part += __shfl_xor(part, d);
  __shared__ float ps[4];
  if ((t & 63) == 0) ps[t >> 6] = part;
  __syncthreads();
  if (t == 0) wsp[blockIdx.x] = ps[0] + ps[1] + ps[2] + ps[3];
}

__global__ void pool2_kernel(const float* __restrict__ wsp, const int* __restrict__ lens,
                             const float* __restrict__ ob, float* __restrict__ out) {
  const int b = threadIdx.x;
  if (b < 16) {
    float s = 0.f;
#pragma unroll
    for (int c = 0; c < 8; ++c) s += wsp[b * 8 + c];
    out[b] = s / (float)lens[b] + ob[0];
  }
}

__global__ void biaspack_kernel(const float* __restrict__ qb, const float* __restrict__ kb,
                                const float* __restrict__ vb, float* __restrict__ qkvb) {
  const int i = blockIdx.x * 256 + threadIdx.x;
  if (i >= 6 * 2304) return;
  const int l = i / 2304, j = i % 2304;
  float v;
  if (j < 768)
    v = qb[l * 768 + j];
  else if (j < 1536)
    v = kb[l * 768 + j - 768];
  else
    v = vb[l * 768 + j - 1536];
  qkvb[i] = v;
}

extern "C" void kernel_launch(void* const* d_in, const int* in_sizes, int n_in, void* d_out,
                              int out_size, void* d_ws, size_t ws_size, hipStream_t stream) {
  const float* x = (const float*)d_in[0];
  const int* lens = (const int*)d_in[1];
  const float* in_w = (const float*)d_in[2];
  const float* in_b = (const float*)d_in[3];
  const float* pos = (const float*)d_in[4];
  const float* qw = (const float*)d_in[5];
  const float* qb = (const float*)d_in[6];
  const float* kw = (const float*)d_in[7];
  const float* kb = (const float*)d_in[8];
  const float* vw = (const float*)d_in[9];
  const float* vb = (const float*)d_in[10];
  const float* w1 = (const float*)d_in[11];
  const float* b1 = (const float*)d_in[12];
  const float* w2 = (const float*)d_in[13];
  const float* b2 = (const float*)d_in[14];
  const float* ln1g = (const float*)d_in[15];
  const float* ln1b = (const float*)d_in[16];
  const float* ln2g = (const float*)d_in[17];
  const float* ln2b = (const float*)d_in[18];
  const float* ow = (const float*)d_in[19];
  const float* ob = (const float*)d_in[20];
  float* out = (float*)d_out;

  char* w = (char*)d_ws;
  size_t off = 0;
  auto alloc = [&](size_t bytes) -> void* {
    void* p = w + off;
    off += (bytes + 255) & ~(size_t)255;
    return p;
  };
  u16* qkvt = (u16*)alloc((size_t)2304 * 768 * 2);
  u16* w1t = (u16*)alloc((size_t)3072 * 768 * 2);
  u16* w2t = (u16*)alloc((size_t)768 * 3072 * 2);
  float* qkvb = (float*)alloc((size_t)6 * 2304 * 4);
  float* h = (float*)alloc((size_t)8192 * 768 * 4);
  u16* hbf = (u16*)alloc((size_t)8192 * 768 * 2);
  float* obuf = (float*)alloc((size_t)2 * 8192 * 768 * 4);  // also FF2 split-K partials
  u16* ubuf = (u16*)alloc((size_t)8192 * 3072 * 2);         // union: qkv / ff
  float* wsp = (float*)alloc((size_t)128 * 4);
  u16* qkvbuf = ubuf;
  u16* ffbuf = ubuf;

  biaspack_kernel<<<(6 * 2304 + 255) / 256, 256, 0, stream>>>(qb, kb, vb, qkvb);
  inproj_kernel<<<1024, 256, 0, stream>>>(x, in_w, in_b, pos, h, hbf);

  for (int l = 0; l < 6; ++l) {
    transpose_qkv_kernel<<<dim3(12, 12, 3), 256, 0, stream>>>(qw, kw, vw, l, qkvt);
    gemm8_kernel<0, 1><<<288, 512, 0, stream>>>(hbf, qkvt, qkvb + l * 2304, qkvbuf, nullptr, 8192,
                                                2304, 768, 768, 1);
    attn_kernel<<<1536, 256, 0, stream>>>(qkvbuf, lens, obuf);
    ln_kernel<1><<<2048, 256, 0, stream>>>(h, obuf, nullptr, ln1g + l * 768, ln1b + l * 768, h,
                                           hbf);
    transpose_one_kernel<<<dim3(48, 12), 256, 0, stream>>>(w1 + (size_t)l * 768 * 3072, w1t, 768,
                                                           3072);
    gemm8_kernel<1, 1><<<384, 512, 0, stream>>>(hbf, w1t, b1 + l * 3072, ffbuf, nullptr, 8192,
                                                3072, 768, 768, 1);
    transpose_one_kernel<<<dim3(12, 48), 256, 0, stream>>>(w2 + (size_t)l * 3072 * 768, w2t, 3072,
                                                           768);
    // FF2 split-K x2: 192 blocks, partials into obuf[0], obuf[1]; summed in ln2
    gemm8_kernel<0, 0><<<192, 512, 0, stream>>>(ffbuf, w2t, b2 + l * 768, nullptr, obuf, 8192, 768,
                                                1536, 3072, 2);
    ln_kernel<2><<<2048, 256, 0, stream>>>(h, obuf, obuf + (size_t)8192 * 768, ln2g + l * 768,
                                           ln2b + l * 768, h, hbf);
  }
  pool1_kernel<<<128, 256, 0, stream>>>(h, lens, ow, wsp);
  pool2_kernel<<<1, 64, 0, stream>>>(wsp, lens, ob, out);
  (void)in_sizes;
  (void)n_in;
  (void)out_size;
  (void)ws_size;
}

// Round 4
// 1426.577 us; speedup vs baseline: 1.3137x; 1.2194x over previous
//
#include <hip/hip_runtime.h>

typedef unsigned short u16;
typedef unsigned int u32;
typedef u16 u16x8 __attribute__((ext_vector_type(8)));
typedef u16 u16x4 __attribute__((ext_vector_type(4)));
typedef __bf16 bf16x8 __attribute__((ext_vector_type(8)));
typedef float f32x4 __attribute__((ext_vector_type(4)));

#define DEV __device__ __forceinline__

DEV u16 f2bf(float f) {
  u32 u = __builtin_bit_cast(u32, f);
  u32 r = u + 0x7fffu + ((u >> 16) & 1u);
  return (u16)(r >> 16);
}

DEV int imin(int a, int b) { return a < b ? a : b; }

DEV void gload_lds16(const void* g, void* l) {
  __builtin_amdgcn_global_load_lds(
      (const __attribute__((address_space(1))) void*)g,
      (__attribute__((address_space(3))) void*)l, 16, 0, 0);
}

// ============ m97-style 128x128 GEMM: C[M,N] = A[M,K] @ Bt[N,K]^T + bias ============
// 256 thr = 4 waves (2M x 2N), per-wave 64x64. BK=64 single-buffer, 32 KiB LDS ->
// 2-3 blocks/CU co-resident; cross-block overlap hides the vmcnt(0) drain (m114).
// LDS XOR-swizzled via pre-swizzled global source (global_load_lds dest is linear).
// nsplit: split-K partials; sp offsets A/Bt cols by sp*ksub, writes Cf+sp*M*N.
template <int RELU, int OUT_BF16>
__global__ __launch_bounds__(256, 3) void gemm97_kernel(
    const u16* __restrict__ A, const u16* __restrict__ Bt,
    const float* __restrict__ bias, u16* __restrict__ Cb, float* __restrict__ Cf,
    int M, int N, int ksub, int ld, int nsplit) {
  __shared__ __align__(16) u16 As[128 * 64];
  __shared__ __align__(16) u16 Bs[128 * 64];
  const int t = threadIdx.x, wave = t >> 6, lane = t & 63;
  const int fr = lane & 15, fq = lane >> 4;
  const int NT = ksub >> 6;
  const int nbx = N >> 7;
  const int tiles = nbx * (M >> 7);

  int bid = blockIdx.x;
  {  // XCD-aware swizzle (all grids here are %8==0)
    const int cpx = (int)gridDim.x >> 3;
    bid = (bid & 7) * cpx + (bid >> 3);
  }
  const int sp = bid / tiles;
  bid -= sp * tiles;
  const int bx = bid % nbx, by = bid / nbx;
  const int m0 = by << 7, n0 = bx << 7;

  // staging: thread t covers LDS row (t>>3)+32*i, 16B slot (t&7); source chunk
  // pre-swizzled so content at (row, slot s) = global chunk (s ^ (row&7))
  const int srow = t >> 3;
  const int c8 = ((t & 7) ^ (srow & 7)) * 8;
  const u16* ag = A + (size_t)sp * ksub + (size_t)(m0 + srow) * ld + c8;
  const u16* bg = Bt + (size_t)sp * ksub + (size_t)(n0 + srow) * ld + c8;
  char* asb = (char*)As + wave * 1024;
  char* bsb = (char*)Bs + wave * 1024;

  const int wr = (wave >> 1) * 64, wc = (wave & 1) * 64;
  f32x4 acc[4][4] = {};

  for (int k0 = 0; k0 < NT; ++k0) {
#pragma unroll
    for (int i = 0; i < 4; ++i) {
      gload_lds16(ag + (size_t)i * 32 * ld, asb + i * 4096);
      gload_lds16(bg + (size_t)i * 32 * ld, bsb + i * 4096);
    }
    ag += 64;
    bg += 64;
    asm volatile("s_waitcnt vmcnt(0)" ::: "memory");
    __syncthreads();
#pragma unroll
    for (int ks = 0; ks < 2; ++ks) {
      bf16x8 af[4], bv[4];
#pragma unroll
      for (int m = 0; m < 4; ++m)
        af[m] = *(const bf16x8*)(As + (wr + m * 16 + fr) * 64 + (((ks * 4 + fq) ^ (fr & 7)) * 8));
#pragma unroll
      for (int n = 0; n < 4; ++n)
        bv[n] = *(const bf16x8*)(Bs + (wc + n * 16 + fr) * 64 + (((ks * 4 + fq) ^ (fr & 7)) * 8));
#pragma unroll
      for (int m = 0; m < 4; ++m)
#pragma unroll
        for (int n = 0; n < 4; ++n)
          acc[m][n] = __builtin_amdgcn_mfma_f32_16x16x32_bf16(af[m], bv[n], acc[m][n], 0, 0, 0);
    }
    __syncthreads();
  }

#pragma unroll
  for (int n = 0; n < 4; ++n) {
    const int col = n0 + wc + n * 16 + fr;
    const float bvv = (nsplit == 1 || sp == 0) ? bias[col] : 0.f;
#pragma unroll
    for (int m = 0; m < 4; ++m) {
#pragma unroll
      for (int r = 0; r < 4; ++r) {
        const int row = m0 + wr + m * 16 + fq * 4 + r;
        float v = acc[m][n][r] + bvv;
        if (RELU) v = fmaxf(v, 0.f);
        if (OUT_BF16)
          Cb[(size_t)row * N + col] = f2bf(v);
        else
          Cf[(size_t)sp * M * N + (size_t)row * N + col] = v;
      }
    }
  }
}

// ---------------- attention: qkv [B,S,2304] bf16 -> o [B,S,768] f32 ----------------
__global__ __launch_bounds__(256, 2) void attn_kernel(const u16* __restrict__ qkv,
                                                      const int* __restrict__ lens,
                                                      float* __restrict__ o) {
  __shared__ __align__(16) u16 Kl[128 * 64];
  __shared__ __align__(16) u16 Vt[64 * 128];
  __shared__ __align__(16) u16 Pl[4][16 * 128];

  const int bid = blockIdx.x;
  const int qt = bid & 7;
  const int h = (bid >> 3) % 12;
  const int b = bid / 96;
  const int len = lens[b];
  const int t = threadIdx.x, wave = t >> 6, lane = t & 63;
  const int fr = lane & 15, fq = lane >> 4;

  const size_t base = (size_t)b * 512 * 2304;
  const int q0 = qt * 64 + wave * 16;

  bf16x8 qf[2];
#pragma unroll
  for (int ks = 0; ks < 2; ++ks)
    qf[ks] = *(const bf16x8*)(qkv + base + (size_t)(q0 + fr) * 2304 + h * 64 + ks * 32 + fq * 8);

  f32x4 oacc[4] = {};
  float mrow[4], lrow[4];
#pragma unroll
  for (int r = 0; r < 4; ++r) {
    mrow[r] = -1e30f;
    lrow[r] = 0.f;
  }

  for (int kv0 = 0; kv0 < 512; kv0 += 128) {
    if (kv0 >= len) break;
#pragma unroll
    for (int i = 0; i < 4; ++i) {
      const int c = i * 256 + t;
      const int row = c >> 3, ch = c & 7;
      u16x8 kvl = *(const u16x8*)(qkv + base + (size_t)(kv0 + row) * 2304 + 768 + h * 64 + ch * 8);
      *(u16x8*)(Kl + row * 64 + ((ch ^ (row & 7)) * 8)) = kvl;
      u16x8 vvl = *(const u16x8*)(qkv + base + (size_t)(kv0 + row) * 2304 + 1536 + h * 64 + ch * 8);
#pragma unroll
      for (int u = 0; u < 8; ++u) {
        const int d = ch * 8 + u;
        Vt[d * 128 + (((row >> 3) ^ (d & 7)) * 8) + (row & 7)] = vvl[u];
      }
    }
    __syncthreads();

    f32x4 sa[8] = {};
#pragma unroll
    for (int ks = 0; ks < 2; ++ks) {
#pragma unroll
      for (int n = 0; n < 8; ++n) {
        const int colr = n * 16 + fr;
        bf16x8 kf = *(const bf16x8*)(Kl + colr * 64 + (((ks * 4 + fq) ^ (colr & 7)) * 8));
        sa[n] = __builtin_amdgcn_mfma_f32_16x16x32_bf16(qf[ks], kf, sa[n], 0, 0, 0);
      }
    }

    float tm[4] = {-1e30f, -1e30f, -1e30f, -1e30f};
#pragma unroll
    for (int n = 0; n < 8; ++n) {
      const int col = kv0 + n * 16 + fr;
      const bool ok = col < len;
#pragma unroll
      for (int r = 0; r < 4; ++r) {
        const float s = ok ? sa[n][r] * 0.125f : -1e30f;
        sa[n][r] = s;
        tm[r] = fmaxf(tm[r], s);
      }
    }
#pragma unroll
    for (int d = 1; d < 16; d <<= 1)
#pragma unroll
      for (int r = 0; r < 4; ++r) tm[r] = fmaxf(tm[r], __shfl_xor(tm[r], d));

    float al[4], rs[4];
#pragma unroll
    for (int r = 0; r < 4; ++r) {
      const float mn = fmaxf(mrow[r], tm[r]);
      al[r] = __expf(mrow[r] - mn);
      mrow[r] = mn;
      rs[r] = 0.f;
    }
#pragma unroll
    for (int n = 0; n < 8; ++n)
#pragma unroll
      for (int r = 0; r < 4; ++r) {
        const float p = __expf(sa[n][r] - mrow[r]);
        sa[n][r] = p;
        rs[r] += p;
      }
#pragma unroll
    for (int d = 1; d < 16; d <<= 1)
#pragma unroll
      for (int r = 0; r < 4; ++r) rs[r] += __shfl_xor(rs[r], d);
#pragma unroll
    for (int r = 0; r < 4; ++r) lrow[r] = lrow[r] * al[r] + rs[r];
#pragma unroll
    for (int n = 0; n < 4; ++n)
#pragma unroll
      for (int r = 0; r < 4; ++r) oacc[n][r] *= al[r];

    u16* P = &Pl[wave][0];
#pragma unroll
    for (int n = 0; n < 8; ++n) {
      const int col = n * 16 + fr;
#pragma unroll
      for (int r = 0; r < 4; ++r) {
        const int row = fq * 4 + r;
        P[row * 128 + (((col >> 3) ^ (row & 7)) * 8) + (col & 7)] = f2bf(sa[n][r]);
      }
    }
#pragma unroll
    for (int kslot = 0; kslot < 4; ++kslot) {
      const int ch = kslot * 4 + fq;
      bf16x8 pa = *(const bf16x8*)(P + fr * 128 + ((ch ^ (fr & 7)) * 8));
#pragma unroll
      for (int n = 0; n < 4; ++n) {
        const int colv = n * 16 + fr;
        bf16x8 vf = *(const bf16x8*)(Vt + colv * 128 + ((ch ^ (colv & 7)) * 8));
        oacc[n] = __builtin_amdgcn_mfma_f32_16x16x32_bf16(pa, vf, oacc[n], 0, 0, 0);
      }
    }
    __syncthreads();
  }

  const size_t obase = (size_t)b * 512 * 768 + (size_t)q0 * 768 + h * 64;
#pragma unroll
  for (int n = 0; n < 4; ++n)
#pragma unroll
    for (int r = 0; r < 4; ++r)
      o[obase + (size_t)(fq * 4 + r) * 768 + n * 16 + fr] = oacc[n][r] / lrow[r];
}

// -------- ALL weight transposes (6 layers x {q,k,v,w1,w2}) in one dispatch --------
// per 64x64 tile: out[n][k] = f2bf(in[k][n])
__global__ __launch_bounds__(256) void transpose_all_kernel(
    const float* __restrict__ qw, const float* __restrict__ kw, const float* __restrict__ vw,
    const float* __restrict__ w1, const float* __restrict__ w2, u16* __restrict__ qkvt6,
    u16* __restrict__ w1t6, u16* __restrict__ w2t6) {
  __shared__ float tile[64][65];
  const int l = blockIdx.y;
  int x = blockIdx.x;
  const float* in;
  u16* op;
  int K, N, nbx;
  if (x < 432) {
    const int which = x / 144;
    x -= which * 144;
    in = (which == 0 ? qw : which == 1 ? kw : vw) + (size_t)l * 768 * 768;
    op = qkvt6 + (size_t)l * 2304 * 768 + (size_t)which * 768 * 768;
    K = 768;
    N = 768;
    nbx = 12;
  } else if (x < 1008) {
    x -= 432;
    in = w1 + (size_t)l * 768 * 3072;
    op = w1t6 + (size_t)l * 3072 * 768;
    K = 768;
    N = 3072;
    nbx = 48;
  } else {
    x -= 1008;
    in = w2 + (size_t)l * 3072 * 768;
    op = w2t6 + (size_t)l * 768 * 3072;
    K = 3072;
    N = 768;
    nbx = 12;
  }
  const int tx = threadIdx.x & 63, ty = threadIdx.x >> 6;
  const int n0 = (x % nbx) * 64, k0 = (x / nbx) * 64;
#pragma unroll
  for (int i = 0; i < 16; ++i)
    tile[ty + i * 4][tx] = in[(size_t)(k0 + ty + i * 4) * N + n0 + tx];
  __syncthreads();
#pragma unroll
  for (int i = 0; i < 16; ++i)
    op[(size_t)(n0 + ty + i * 4) * K + k0 + tx] = f2bf(tile[tx][ty + i * 4]);
}

// ---------------- input projection ----------------
__global__ __launch_bounds__(256) void inproj_kernel(const float* __restrict__ x,
                                                     const float* __restrict__ in_w,
                                                     const float* __restrict__ in_b,
                                                     const float* __restrict__ pos,
                                                     float* __restrict__ h,
                                                     u16* __restrict__ hbf) {
  __shared__ float xs[8][32];
  const int t = threadIdx.x;
  const int row0 = blockIdx.x * 8;
  xs[t >> 5][t & 31] = x[(size_t)row0 * 32 + t];
  __syncthreads();
#pragma unroll
  for (int j = 0; j < 3; ++j) {
    const int d = t + j * 256;
    float acc[8] = {};
#pragma unroll
    for (int i = 0; i < 32; ++i) {
      const float wv = in_w[i * 768 + d];
#pragma unroll
      for (int r = 0; r < 8; ++r) acc[r] += xs[r][i] * wv;
    }
    const float bb = in_b[d];
#pragma unroll
    for (int r = 0; r < 8; ++r) {
      const int row = row0 + r;
      const int s = row & 511;
      const float v = acc[r] + bb + pos[(size_t)s * 768 + d];
      h[(size_t)row * 768 + d] = v;
      hbf[(size_t)row * 768 + d] = f2bf(v);
    }
  }
}

// ---------------- LayerNorm(hin + d0 [+ d1]): wave-per-row, f32x4 ----------------
template <int ND>
__global__ __launch_bounds__(256) void ln_kernel(const float* __restrict__ hin,
                                                 const float* __restrict__ d0,
                                                 const float* __restrict__ d1,
                                                 const float* __restrict__ g,
                                                 const float* __restrict__ bb,
                                                 float* __restrict__ hout,
                                                 u16* __restrict__ hbf) {
  const int row = blockIdx.x * 4 + (threadIdx.x >> 6);
  const int lane = threadIdx.x & 63;
  const size_t rb = (size_t)row * 768 + lane * 4;
  f32x4 xv[3];
  float s = 0.f, s2 = 0.f;
#pragma unroll
  for (int j = 0; j < 3; ++j) {
    f32x4 a = *(const f32x4*)(hin + rb + j * 256);
    f32x4 d = *(const f32x4*)(d0 + rb + j * 256);
    f32x4 v = a + d;
    if (ND == 2) {
      f32x4 e = *(const f32x4*)(d1 + rb + j * 256);
      v = v + e;
    }
    xv[j] = v;
    s += v[0] + v[1] + v[2] + v[3];
    s2 += v[0] * v[0] + v[1] * v[1] + v[2] * v[2] + v[3] * v[3];
  }
#pragma unroll
  for (int d = 1; d < 64; d <<= 1) {
    s += __shfl_xor(s, d);
    s2 += __shfl_xor(s2, d);
  }
  const float mean = s * (1.f / 768.f);
  const float var = fmaxf(s2 * (1.f / 768.f) - mean * mean, 0.f);
  const float rstd = rsqrtf(var + 1e-5f);
#pragma unroll
  for (int j = 0; j < 3; ++j) {
    f32x4 gv = *(const f32x4*)(g + lane * 4 + j * 256);
    f32x4 bv = *(const f32x4*)(bb + lane * 4 + j * 256);
    f32x4 y;
    u16x4 yb;
#pragma unroll
    for (int c = 0; c < 4; ++c) {
      y[c] = (xv[j][c] - mean) * rstd * gv[c] + bv[c];
      yb[c] = f2bf(y[c]);
    }
    *(f32x4*)(hout + rb + j * 256) = y;
    *(u16x4*)(hbf + rb + j * 256) = yb;
  }
}

// ---------------- masked mean pool + out projection (2-stage) ----------------
__global__ __launch_bounds__(256) void pool1_kernel(const float* __restrict__ h,
                                                    const int* __restrict__ lens,
                                                    const float* __restrict__ ow,
                                                    float* __restrict__ wsp) {
  const int b = blockIdx.x >> 3, chunk = blockIdx.x & 7;
  const int len = lens[b];
  const int t = threadIdx.x;
  const int s0 = chunk * 64;
  const int s1 = imin(s0 + 64, len);
  float acc0 = 0.f, acc1 = 0.f, acc2 = 0.f;
  const float* hp = h + (size_t)b * 512 * 768;
  for (int s = s0; s < s1; ++s) {
    const size_t rb = (size_t)s * 768;
    acc0 += hp[rb + t];
    acc1 += hp[rb + t + 256];
    acc2 += hp[rb + t + 512];
  }
  float part = acc0 * ow[t] + acc1 * ow[t + 256] + acc2 * ow[t + 512];
#pragma unroll
  for (int d = 1; d < 64; d <<= 1) part += __shfl_xor(part, d);
  __shared__ float ps[4];
  if ((t & 63) == 0) ps[t >> 6] = part;
  __syncthreads();
  if (t == 0) wsp[blockIdx.x] = ps[0] + ps[1] + ps[2] + ps[3];
}

__global__ void pool2_kernel(const float* __restrict__ wsp, const int* __restrict__ lens,
                             const float* __restrict__ ob, float* __restrict__ out) {
  const int b = threadIdx.x;
  if (b < 16) {
    float s = 0.f;
#pragma unroll
    for (int c = 0; c < 8; ++c) s += wsp[b * 8 + c];
    out[b] = s / (float)lens[b] + ob[0];
  }
}

__global__ void biaspack_kernel(const float* __restrict__ qb, const float* __restrict__ kb,
                                const float* __restrict__ vb, float* __restrict__ qkvb) {
  const int i = blockIdx.x * 256 + threadIdx.x;
  if (i >= 6 * 2304) return;
  const int l = i / 2304, j = i % 2304;
  float v;
  if (j < 768)
    v = qb[l * 768 + j];
  else if (j < 1536)
    v = kb[l * 768 + j - 768];
  else
    v = vb[l * 768 + j - 1536];
  qkvb[i] = v;
}

extern "C" void kernel_launch(void* const* d_in, const int* in_sizes, int n_in, void* d_out,
                              int out_size, void* d_ws, size_t ws_size, hipStream_t stream) {
  const float* x = (const float*)d_in[0];
  const int* lens = (const int*)d_in[1];
  const float* in_w = (const float*)d_in[2];
  const float* in_b = (const float*)d_in[3];
  const float* pos = (const float*)d_in[4];
  const float* qw = (const float*)d_in[5];
  const float* qb = (const float*)d_in[6];
  const float* kw = (const float*)d_in[7];
  const float* kb = (const float*)d_in[8];
  const float* vw = (const float*)d_in[9];
  const float* vb = (const float*)d_in[10];
  const float* w1 = (const float*)d_in[11];
  const float* b1 = (const float*)d_in[12];
  const float* w2 = (const float*)d_in[13];
  const float* b2 = (const float*)d_in[14];
  const float* ln1g = (const float*)d_in[15];
  const float* ln1b = (const float*)d_in[16];
  const float* ln2g = (const float*)d_in[17];
  const float* ln2b = (const float*)d_in[18];
  const float* ow = (const float*)d_in[19];
  const float* ob = (const float*)d_in[20];
  float* out = (float*)d_out;

  char* w = (char*)d_ws;
  size_t off = 0;
  auto alloc = [&](size_t bytes) -> void* {
    void* p = w + off;
    off += (bytes + 255) & ~(size_t)255;
    return p;
  };
  u16* qkvt6 = (u16*)alloc((size_t)6 * 2304 * 768 * 2);
  u16* w1t6 = (u16*)alloc((size_t)6 * 3072 * 768 * 2);
  u16* w2t6 = (u16*)alloc((size_t)6 * 768 * 3072 * 2);
  float* qkvb = (float*)alloc((size_t)6 * 2304 * 4);
  float* h = (float*)alloc((size_t)8192 * 768 * 4);
  u16* hbf = (u16*)alloc((size_t)8192 * 768 * 2);
  float* obuf = (float*)alloc((size_t)2 * 8192 * 768 * 4);  // also FF2 split-K partials
  u16* ubuf = (u16*)alloc((size_t)8192 * 3072 * 2);         // union: qkv / ff
  float* wsp = (float*)alloc((size_t)128 * 4);
  u16* qkvbuf = ubuf;
  u16* ffbuf = ubuf;

  biaspack_kernel<<<(6 * 2304 + 255) / 256, 256, 0, stream>>>(qb, kb, vb, qkvb);
  transpose_all_kernel<<<dim3(1584, 6), 256, 0, stream>>>(qw, kw, vw, w1, w2, qkvt6, w1t6, w2t6);
  inproj_kernel<<<1024, 256, 0, stream>>>(x, in_w, in_b, pos, h, hbf);

  for (int l = 0; l < 6; ++l) {
    // QKV: 64x18 = 1152 tile-blocks, all co-resident at 2-3 blocks/CU
    gemm97_kernel<0, 1><<<1152, 256, 0, stream>>>(hbf, qkvt6 + (size_t)l * 2304 * 768,
                                                  qkvb + l * 2304, qkvbuf, nullptr, 8192, 2304,
                                                  768, 768, 1);
    attn_kernel<<<1536, 256, 0, stream>>>(qkvbuf, lens, obuf);
    ln_kernel<1><<<2048, 256, 0, stream>>>(h, obuf, nullptr, ln1g + l * 768, ln1b + l * 768, h,
                                           hbf);
    // FF1: 64x24 = 1536 blocks
    gemm97_kernel<1, 1><<<1536, 256, 0, stream>>>(hbf, w1t6 + (size_t)l * 3072 * 768,
                                                  b1 + l * 3072, ffbuf, nullptr, 8192, 3072, 768,
                                                  768, 1);
    // FF2 split-K x2: 64x6x2 = 768 blocks, partials summed in ln2
    gemm97_kernel<0, 0><<<768, 256, 0, stream>>>(ffbuf, w2t6 + (size_t)l * 768 * 3072,
                                                 b2 + l * 768, nullptr, obuf, 8192, 768, 1536,
                                                 3072, 2);
    ln_kernel<2><<<2048, 256, 0, stream>>>(h, obuf, obuf + (size_t)8192 * 768, ln2g + l * 768,
                                           ln2b + l * 768, h, hbf);
  }
  pool1_kernel<<<128, 256, 0, stream>>>(h, lens, ow, wsp);
  pool2_kernel<<<1, 64, 0, stream>>>(wsp, lens, ob, out);
  (void)in_sizes;
  (void)n_in;
  (void)out_size;
  (void)ws_size;
}